// Round 1
// baseline (148.932 us; speedup 1.0000x reference)
//
#include <hip/hip_runtime.h>
#include <hip/hip_bf16.h>

// Problem constants (match reference)
#define BB 2
#define CC 128
#define HH 96
#define WW 96
#define HEADS 4
#define DHEAD 32
#define WIN 5
#define PADW 2
#define PP (HH * WW)          // 9216 pixels per batch
#define INNER (HEADS * DHEAD) // 128

// ---------------------------------------------------------------------------
// GEMM: Out[b][n][p] = sum_k W[n][k] * X[b][k][p],  Cin = 128 fixed.
// W selected from {W0,W1,W2} by n/128 (for QKV); for proj pass same ptr.
// Tile: 64 n  x 128 p per block, K-step 32. 256 threads, 4x8 microtile.
// ---------------------------------------------------------------------------
__global__ __launch_bounds__(256) void gemm_nk(
    const float* __restrict__ X,
    const float* __restrict__ W0, const float* __restrict__ W1,
    const float* __restrict__ W2,
    float* __restrict__ Out, int ntot)
{
    __shared__ float sW[32][68];   // transposed W tile: sW[k][n], padded stride
    __shared__ float sX[32][128];  // sX[k][p]

    const int tp0 = blockIdx.x * 128;
    const int n0  = blockIdx.y * 64;
    const int b   = blockIdx.z;

    const int sel = n0 >> 7;
    const float* Wsel = (sel == 0) ? W0 : ((sel == 1) ? W1 : W2);
    const int nloc = n0 & 127;

    const float* Xb = X + (size_t)b * (CC * PP);
    float* Ob = Out + (size_t)b * ntot * PP;

    const int t = threadIdx.x;
    const int pg = t & 15;        // pixel group 0..15
    const int ng = t >> 4;        // n group 0..15
    const int pbase = pg * 8;
    const int nbase = ng * 4;

    float acc[4][8];
    #pragma unroll
    for (int i = 0; i < 4; i++)
        #pragma unroll
        for (int j = 0; j < 8; j++) acc[i][j] = 0.f;

    for (int k0 = 0; k0 < 128; k0 += 32) {
        // --- stage W tile (64 n x 32 k), transposed into sW[k][n] ---
        #pragma unroll
        for (int i = 0; i < 2; i++) {
            int idx = t + 256 * i;          // 0..511 float4s
            int n  = idx >> 3;              // 0..63
            int k4 = idx & 7;               // float4 within k-strip
            float4 w4 = *(const float4*)(Wsel + (nloc + n) * 128 + k0 + k4 * 4);
            sW[k4 * 4 + 0][n] = w4.x;
            sW[k4 * 4 + 1][n] = w4.y;
            sW[k4 * 4 + 2][n] = w4.z;
            sW[k4 * 4 + 3][n] = w4.w;
        }
        // --- stage X tile (32 k x 128 p) ---
        #pragma unroll
        for (int i = 0; i < 4; i++) {
            int idx = t + 256 * i;          // 0..1023 float4s
            int kr = idx >> 5;              // 0..31
            int c4 = idx & 31;
            *(float4*)&sX[kr][c4 * 4] =
                *(const float4*)(Xb + (size_t)(k0 + kr) * PP + tp0 + c4 * 4);
        }
        __syncthreads();

        #pragma unroll
        for (int kk = 0; kk < 32; kk++) {
            float xv[8], wv[4];
            *(float4*)&xv[0] = *(float4*)&sX[kk][pbase];
            *(float4*)&xv[4] = *(float4*)&sX[kk][pbase + 4];
            *(float4*)&wv[0] = *(float4*)&sW[kk][nbase];
            #pragma unroll
            for (int i = 0; i < 4; i++)
                #pragma unroll
                for (int j = 0; j < 8; j++)
                    acc[i][j] += wv[i] * xv[j];
        }
        __syncthreads();
    }

    #pragma unroll
    for (int i = 0; i < 4; i++) {
        float* dst = Ob + (size_t)(n0 + nbase + i) * PP + tp0 + pbase;
        *(float4*)dst       = make_float4(acc[i][0], acc[i][1], acc[i][2], acc[i][3]);
        *(float4*)(dst + 4) = make_float4(acc[i][4], acc[i][5], acc[i][6], acc[i][7]);
    }
}

// ---------------------------------------------------------------------------
// Windowed attention. One block per (8x8 pixel tile, b, h).
// qkv layout: [b][384][P] with q at o=0..127 (o = h*32+d), k at +128, v at +256.
// ao layout: [b][128][P].
// ---------------------------------------------------------------------------
__global__ __launch_bounds__(256) void attn_win(
    const float* __restrict__ qkv, float* __restrict__ ao)
{
    __shared__ float sK[32][144];   // [d][halo pos], halo 12x12
    __shared__ float sV[32][144];
    __shared__ float sQ[32][64];    // [d][local px]
    __shared__ float sS[64][26];    // scores, padded

    const int t  = threadIdx.x;
    const int x0 = blockIdx.x * 8;
    const int y0 = blockIdx.y * 8;
    const int b  = blockIdx.z >> 2;
    const int h  = blockIdx.z & 3;

    const float* qb = qkv + ((size_t)b * 384 + h * DHEAD) * PP;
    const float* kb = qb + 128 * PP;
    const float* vb = qb + 256 * PP;

    // stage K,V halo (32 d x 144 pos); zero-fill out-of-bounds (reference pads 0)
    for (int i = t; i < 32 * 144; i += 256) {
        int d = i / 144, pos = i % 144;
        int gy = y0 - PADW + pos / 12;
        int gx = x0 - PADW + pos % 12;
        bool in = (gy >= 0) & (gy < HH) & (gx >= 0) & (gx < WW);
        int gp = gy * WW + gx;
        sK[d][pos] = in ? kb[d * PP + gp] : 0.f;
        sV[d][pos] = in ? vb[d * PP + gp] : 0.f;
    }
    // stage Q (32 d x 64 px)
    for (int i = t; i < 32 * 64; i += 256) {
        int d = i >> 6, px = i & 63;
        int gy = y0 + (px >> 3), gx = x0 + (px & 7);
        sQ[d][px] = qb[d * PP + gy * WW + gx];
    }
    __syncthreads();

    const int px = t & 63;
    const int wv = t >> 6;           // wave id 0..3
    const int ly = px >> 3, lx = px & 7;
    const float scale = 0.17677669529663689f; // 1/sqrt(32)

    // scores: each wave handles positions wv, wv+4, ...
    for (int pos = wv; pos < 25; pos += 4) {
        int hp = (ly + pos / 5) * 12 + lx + pos % 5;
        float s = 0.f;
        #pragma unroll
        for (int d = 0; d < 32; d++) s += sQ[d][px] * sK[d][hp];
        sS[px][pos] = s * scale;
    }
    __syncthreads();

    // softmax over 25 positions, one thread per pixel (wave 0)
    if (t < 64) {
        float m = -1e30f;
        #pragma unroll
        for (int p = 0; p < 25; p++) m = fmaxf(m, sS[t][p]);
        float e[25]; float sum = 0.f;
        #pragma unroll
        for (int p = 0; p < 25; p++) { e[p] = __expf(sS[t][p] - m); sum += e[p]; }
        float inv = 1.f / sum;
        #pragma unroll
        for (int p = 0; p < 25; p++) sS[t][p] = e[p] * inv;
    }
    __syncthreads();

    // out: attn . V  (each thread: fixed px, d = wv, wv+4, ...)
    float at[25];
    #pragma unroll
    for (int p = 0; p < 25; p++) at[p] = sS[px][p];

    float* aob = ao + ((size_t)b * 128 + h * DHEAD) * PP;
    const int gp = (y0 + ly) * WW + x0 + lx;
    for (int d = wv; d < 32; d += 4) {
        float acc = 0.f;
        #pragma unroll
        for (int p = 0; p < 25; p++) {
            int hp = (ly + p / 5) * 12 + lx + p % 5;
            acc += at[p] * sV[d][hp];
        }
        aob[d * PP + gp] = acc;
    }
}

extern "C" void kernel_launch(void* const* d_in, const int* in_sizes, int n_in,
                              void* d_out, int out_size, void* d_ws, size_t ws_size,
                              hipStream_t stream)
{
    const float* x     = (const float*)d_in[0];
    const float* wq    = (const float*)d_in[1];
    const float* wk    = (const float*)d_in[2];
    const float* wv    = (const float*)d_in[3];
    const float* wproj = (const float*)d_in[4];
    float* out = (float*)d_out;

    float* ws  = (float*)d_ws;
    float* qkv = ws;                          // [B][384][P]
    float* ao  = ws + (size_t)BB * 384 * PP;  // [B][128][P]

    // 1) QKV projection: n = 0..383 (q|k|v), per-pixel linear map
    gemm_nk<<<dim3(PP / 128, 384 / 64, BB), 256, 0, stream>>>(x, wq, wk, wv, qkv, 384);
    // 2) windowed attention
    attn_win<<<dim3(WW / 8, HH / 8, BB * HEADS), 256, 0, stream>>>(qkv, ao);
    // 3) output projection
    gemm_nk<<<dim3(PP / 128, 128 / 64, BB), 256, 0, stream>>>(ao, wproj, wproj, wproj, out, 128);
}

// Round 2
// 107.773 us; speedup vs baseline: 1.3819x; 1.3819x over previous
//
#include <hip/hip_runtime.h>
#include <hip/hip_bf16.h>
#include <hip/hip_fp16.h>

#define PP 9216   // 96*96 pixels per batch
#define OO 384    // qkv channels

typedef _Float16 f16x8 __attribute__((ext_vector_type(8)));
typedef _Float16 h2    __attribute__((ext_vector_type(2)));
typedef float    f32x4 __attribute__((ext_vector_type(4)));

#if defined(__has_builtin)
# if __has_builtin(__builtin_amdgcn_fdot2)
#  define HAS_FDOT2 1
# endif
#endif

__device__ __forceinline__ float dot2acc(h2 a, h2 b, float c) {
#ifdef HAS_FDOT2
    return __builtin_amdgcn_fdot2(a, b, c, false);
#else
    return c + (float)a[0] * (float)b[0] + (float)a[1] * (float)b[1];
#endif
}

// ---------------------------------------------------------------------------
// prep: (y<4) transpose x[b][c][p] f32 -> xT[b][p][c] f16 in 32x32 tiles;
//       (y==4,z==0) convert weights to f16 (wq|wk|wv concat rows, wproj).
// ---------------------------------------------------------------------------
__global__ __launch_bounds__(256) void prep(
    const float* __restrict__ x, const float* __restrict__ wq,
    const float* __restrict__ wk, const float* __restrict__ wv,
    const float* __restrict__ wp,
    _Float16* __restrict__ xT, _Float16* __restrict__ wqkv,
    _Float16* __restrict__ wproj)
{
    const int t = threadIdx.x;
    if (blockIdx.y == 4) {
        if (blockIdx.z) return;
        int idx = blockIdx.x * 256 + t;
        if (idx < 49152) {
            int o = idx >> 7;
            const float* src = (o < 128) ? wq : ((o < 256) ? wk : wv);
            wqkv[idx] = (_Float16)src[(o & 127) * 128 + (idx & 127)];
        } else if (idx < 65536) {
            int j = idx - 49152;
            wproj[j] = (_Float16)wp[j];
        }
        return;
    }
    __shared__ float sT[32][33];
    const int p0 = blockIdx.x * 32;
    const int c0 = blockIdx.y * 32;
    const int b  = blockIdx.z;
    const int row = t >> 3, col = t & 7;

    const float* xb = x + (size_t)b * 128 * PP;
    float4 v = *(const float4*)(xb + (size_t)(c0 + row) * PP + p0 + col * 4);
    sT[col * 4 + 0][row] = v.x;
    sT[col * 4 + 1][row] = v.y;
    sT[col * 4 + 2][row] = v.z;
    sT[col * 4 + 3][row] = v.w;
    __syncthreads();

    _Float16 h[4];
    #pragma unroll
    for (int j = 0; j < 4; j++) h[j] = (_Float16)sT[row][col * 4 + j];
    *(ushort4*)(xT + (size_t)b * PP * 128 + (size_t)(p0 + row) * 128 + c0 + col * 4) =
        *(ushort4*)h;
}

// ---------------------------------------------------------------------------
// QKV GEMM: qkv[b][p][o] = sum_c xT[b][p][c] * wqkv[o][c], f16 MFMA, no LDS.
// Block: 64px x 192o. Wave: 32px x 96o (2 m-subtiles x 6 n-tiles).
// ---------------------------------------------------------------------------
__global__ __launch_bounds__(256) void qkv_gemm(
    const _Float16* __restrict__ xT, const _Float16* __restrict__ wqkv,
    _Float16* __restrict__ qkv)
{
    const int b = blockIdx.z;
    const int p0 = blockIdx.x * 64;
    const int nbase = blockIdx.y * 192;
    const int t = threadIdx.x;
    const int w = t >> 6, lane = t & 63;
    const int lm = lane & 15, quad = lane >> 4;
    const int ms0 = (w & 1) * 32;
    const int nw = (w >> 1) * 96;

    const _Float16* xb = xT + (size_t)b * PP * 128;
    _Float16* qb = qkv + (size_t)b * PP * OO;

    f16x8 A[2][4];
    #pragma unroll
    for (int ms = 0; ms < 2; ms++)
        #pragma unroll
        for (int kc = 0; kc < 4; kc++)
            A[ms][kc] = *(const f16x8*)(xb + (size_t)(p0 + ms0 + ms * 16 + lm) * 128
                                        + kc * 32 + quad * 8);

    for (int nt = 0; nt < 6; nt++) {
        const int n0 = nbase + nw + nt * 16;
        f16x8 Bf[4];
        #pragma unroll
        for (int kc = 0; kc < 4; kc++)
            Bf[kc] = *(const f16x8*)(wqkv + (size_t)(n0 + lm) * 128 + kc * 32 + quad * 8);
        f32x4 acc[2];
        #pragma unroll
        for (int ms = 0; ms < 2; ms++) {
            acc[ms] = (f32x4){0.f, 0.f, 0.f, 0.f};
            #pragma unroll
            for (int kc = 0; kc < 4; kc++)
                acc[ms] = __builtin_amdgcn_mfma_f32_16x16x32_f16(A[ms][kc], Bf[kc], acc[ms], 0, 0, 0);
        }
        #pragma unroll
        for (int ms = 0; ms < 2; ms++)
            #pragma unroll
            for (int r = 0; r < 4; r++)
                qb[(size_t)(p0 + ms0 + ms * 16 + quad * 4 + r) * OO + n0 + lm] =
                    (_Float16)acc[ms][r];
    }
}

// ---------------------------------------------------------------------------
// Windowed attention v2. qkv[b][p][384] f16 (q:0-127,k:128-255,v:256-383,
// each h*32+d). One block per (8x8 tile, b, h). ao[b][p][128] f16.
// ---------------------------------------------------------------------------
__global__ __launch_bounds__(256) void attn2(
    const _Float16* __restrict__ qkv, _Float16* __restrict__ ao)
{
    __shared__ _Float16 sK[144 * 40];
    __shared__ _Float16 sV[144 * 40];
    __shared__ float sS[64 * 28];

    const int t = threadIdx.x;
    const int x0 = blockIdx.x * 8, y0 = blockIdx.y * 8;
    const int b = blockIdx.z >> 2, h = blockIdx.z & 3;
    const _Float16* base = qkv + (size_t)b * PP * OO;

    // stage K,V halo: 144 pos x 32 halfs each, contiguous 64B rows
    for (int u = t; u < 288; u += 256) {
        const int arr = (u >= 144) ? 1 : 0;
        const int pos = u - 144 * arr;
        const int gy = y0 - 2 + pos / 12;
        const int gx = x0 - 2 + pos % 12;
        _Float16* dst = (arr ? sV : sK) + pos * 40;
        if ((unsigned)gy < 96u && (unsigned)gx < 96u) {
            const _Float16* src = base + (size_t)(gy * 96 + gx) * OO + 128 + arr * 128 + h * 32;
            #pragma unroll
            for (int j = 0; j < 4; j++)
                *(uint4*)(dst + j * 8) = *(const uint4*)(src + j * 8);
        } else {
            uint4 z = {0u, 0u, 0u, 0u};
            #pragma unroll
            for (int j = 0; j < 4; j++) *(uint4*)(dst + j * 8) = z;
        }
    }

    const int px = t & 63, w = t >> 6;
    const int ly = px >> 3, lx = px & 7;
    const int gp = (y0 + ly) * 96 + x0 + lx;

    // Q into registers (16 x half2)
    h2 qreg[16];
    {
        const _Float16* qs = base + (size_t)gp * OO + h * 32;
        #pragma unroll
        for (int j = 0; j < 4; j++)
            *(uint4*)(&qreg[j * 4]) = *(const uint4*)(qs + j * 8);
    }
    __syncthreads();

    // scores: wave w handles pos = w, w+4, ...
    const float scale = 0.17677669529663689f;
    for (int pos = w; pos < 25; pos += 4) {
        const int hp = (ly + pos / 5) * 12 + lx + pos % 5;
        const _Float16* kr = sK + hp * 40;
        h2 kreg[16];
        #pragma unroll
        for (int j = 0; j < 4; j++)
            *(uint4*)(&kreg[j * 4]) = *(const uint4*)(kr + j * 8);
        float s0 = 0.f, s1 = 0.f;
        #pragma unroll
        for (int j = 0; j < 8; j++) {
            s0 = dot2acc(qreg[2 * j], kreg[2 * j], s0);
            s1 = dot2acc(qreg[2 * j + 1], kreg[2 * j + 1], s1);
        }
        sS[px * 28 + pos] = (s0 + s1) * scale;
    }
    __syncthreads();

    // softmax over 25 positions (one thread per pixel)
    if (t < 64) {
        float* row = sS + t * 28;
        float m = row[0];
        #pragma unroll
        for (int p = 1; p < 25; p++) m = fmaxf(m, row[p]);
        float sum = 0.f;
        float e[25];
        #pragma unroll
        for (int p = 0; p < 25; p++) { e[p] = __expf(row[p] - m); sum += e[p]; }
        const float inv = 1.f / sum;
        #pragma unroll
        for (int p = 0; p < 25; p++) row[p] = e[p] * inv;
    }
    __syncthreads();

    // PV: wave w handles d in [w*8, w*8+8)
    float at[25];
    #pragma unroll
    for (int p = 0; p < 25; p++) at[p] = sS[px * 28 + p];

    float f[8];
    #pragma unroll
    for (int j = 0; j < 8; j++) f[j] = 0.f;
    for (int p = 0; p < 25; p++) {
        const int hp = (ly + p / 5) * 12 + lx + p % 5;
        h2 vreg[4];
        *(uint4*)vreg = *(const uint4*)(sV + hp * 40 + w * 8);
        #pragma unroll
        for (int j = 0; j < 4; j++) {
            f[2 * j]     += at[p] * (float)vreg[j][0];
            f[2 * j + 1] += at[p] * (float)vreg[j][1];
        }
    }
    _Float16 ho[8];
    #pragma unroll
    for (int j = 0; j < 8; j++) ho[j] = (_Float16)f[j];
    *(uint4*)(ao + ((size_t)b * PP + gp) * 128 + h * 32 + w * 8) = *(uint4*)ho;
}

// ---------------------------------------------------------------------------
// Proj GEMM: out[b][c][p] = sum_o wproj[c][o] * ao[b][p][o], fp32 out.
// Block: 64px x 128c. Wave: 32px x 64c.
// ---------------------------------------------------------------------------
__global__ __launch_bounds__(256) void proj_gemm(
    const _Float16* __restrict__ ao, const _Float16* __restrict__ wproj,
    float* __restrict__ out)
{
    const int b = blockIdx.z;
    const int p0 = blockIdx.x * 64;
    const int t = threadIdx.x;
    const int w = t >> 6, lane = t & 63;
    const int lm = lane & 15, quad = lane >> 4;
    const int ms0 = (w & 1) * 32;
    const int nw = (w >> 1) * 64;

    const _Float16* ab = ao + (size_t)b * PP * 128;
    float* ob = out + (size_t)b * 128 * PP;

    f16x8 A[2][4];
    #pragma unroll
    for (int ms = 0; ms < 2; ms++)
        #pragma unroll
        for (int kc = 0; kc < 4; kc++)
            A[ms][kc] = *(const f16x8*)(ab + (size_t)(p0 + ms0 + ms * 16 + lm) * 128
                                        + kc * 32 + quad * 8);

    for (int nt = 0; nt < 4; nt++) {
        const int n0 = nw + nt * 16;
        f16x8 Bf[4];
        #pragma unroll
        for (int kc = 0; kc < 4; kc++)
            Bf[kc] = *(const f16x8*)(wproj + (size_t)(n0 + lm) * 128 + kc * 32 + quad * 8);
        f32x4 acc[2];
        #pragma unroll
        for (int ms = 0; ms < 2; ms++) {
            acc[ms] = (f32x4){0.f, 0.f, 0.f, 0.f};
            #pragma unroll
            for (int kc = 0; kc < 4; kc++)
                acc[ms] = __builtin_amdgcn_mfma_f32_16x16x32_f16(A[ms][kc], Bf[kc], acc[ms], 0, 0, 0);
        }
        #pragma unroll
        for (int ms = 0; ms < 2; ms++) {
            float4 v = make_float4(acc[ms][0], acc[ms][1], acc[ms][2], acc[ms][3]);
            *(float4*)(ob + (size_t)(n0 + lm) * PP + p0 + ms0 + ms * 16 + quad * 4) = v;
        }
    }
}

extern "C" void kernel_launch(void* const* d_in, const int* in_sizes, int n_in,
                              void* d_out, int out_size, void* d_ws, size_t ws_size,
                              hipStream_t stream)
{
    const float* x  = (const float*)d_in[0];
    const float* wq = (const float*)d_in[1];
    const float* wk = (const float*)d_in[2];
    const float* wv = (const float*)d_in[3];
    const float* wp = (const float*)d_in[4];
    float* out = (float*)d_out;

    _Float16* ws    = (_Float16*)d_ws;
    _Float16* xT    = ws;                       // 2*9216*128
    _Float16* wqkv  = xT + 2359296;             // 384*128
    _Float16* wproj = wqkv + 49152;             // 128*128
    _Float16* qkvh  = wproj + 16384;            // 2*9216*384
    _Float16* aoh   = qkvh + 7077888;           // 2*9216*128

    prep<<<dim3(288, 5, 2), 256, 0, stream>>>(x, wq, wk, wv, wp, xT, wqkv, wproj);
    qkv_gemm<<<dim3(144, 2, 2), 256, 0, stream>>>(xT, wqkv, qkvh);
    attn2<<<dim3(12, 12, 8), 256, 0, stream>>>(qkvh, aoh);
    proj_gemm<<<dim3(144, 1, 2), 256, 0, stream>>>(aoh, wproj, out);
}